// Round 3
// baseline (1566.332 us; speedup 1.0000x reference)
//
#include <hip/hip_runtime.h>

// DBRX attention layer: B=1, T=2048, D_MODEL=6144, NH=48, NKV=8, HD=128,
// rope_base=5e5 full-dim, clamp +-8, causal, f32 in/out, bf16 MFMA compute.

typedef __attribute__((ext_vector_type(8))) short bf16x8;
typedef __attribute__((ext_vector_type(4))) float f32x4;

__device__ inline short f2bf(float f) {
  union { float f; unsigned u; } v; v.f = f;
  unsigned r = v.u + 0x7fffu + ((v.u >> 16) & 1u);  // round-to-nearest-even
  return (short)(r >> 16);
}

// ---------------- f32 -> bf16 convert (8 elems/thread) ----------------
__global__ void cvt_bf16(const float* __restrict__ in, short* __restrict__ out, int n8) {
  int i = blockIdx.x * 256 + threadIdx.x;
  if (i >= n8) return;
  const float4* p = (const float4*)in;
  float4 a = p[2 * i], b = p[2 * i + 1];
  bf16x8 r;
  r[0] = f2bf(a.x); r[1] = f2bf(a.y); r[2] = f2bf(a.z); r[3] = f2bf(a.w);
  r[4] = f2bf(b.x); r[5] = f2bf(b.y); r[6] = f2bf(b.z); r[7] = f2bf(b.w);
  *((bf16x8*)out + i) = r;
}

// ============ bf16 GEMM, B^T input — 256x256 double-buffer, 1 barrier/tile ====
// A: MxK row-major bf16, B: NxK row-major bf16 (B^T), C: MxN f32.
// BM=BN=256, BK=64. 512 thr = 8 waves (2M x 4N), per-wave 128x64 out
// (8x4 frags of 16x16x32). LDS: 2 buffers x (A 32KB + B 32KB) = 128 KiB.
// Sync: ONE __syncthreads per K-tile (its implicit vmcnt(0) drains tile t+1's
// prefetch, which was issued a full tile-compute earlier -> no stall). No
// sched pinning inside the tile: compiler interleaves ds_read/MFMA (r109).
// T2 swizzle: byte ^= (row&7)<<4; linear LDS dest + inverse-swizzled global
// source (rule 21 both-sides). Verified conflict-free (round 2: conflicts=0).
__device__ __forceinline__ void gload_lds16(const short* g, short* l) {
  __builtin_amdgcn_global_load_lds(
      (const __attribute__((address_space(1))) void*)g,
      (__attribute__((address_space(3))) void*)l, 16, 0, 0);
}

__device__ __forceinline__ bf16x8 frag_ld(const short* buf, int row, int kb) {
  // buf rows are 64 elems = 128 B; kb = byte offset in row (ks*64 + quad*16)
  int off = row * 128 + (kb ^ ((row & 7) << 4));
  return *(const bf16x8*)((const char*)buf + off);
}

__device__ __forceinline__ void tile256(
    int t, int nt, const short* Ac, const short* Bc, short* An, short* Bn,
    const short* const srcA[4], const short* const srcB[4], const int ldso[4],
    int wm, int wn, int lm, int quad, f32x4 acc[8][4]) {
  // stage tile t+1 into the other buffer (read last during t-1; all waves
  // passed the t-1 end barrier -> write-safe)
  if (t + 1 < nt) {
    const int koff = (t + 1) << 6;
#pragma unroll
    for (int i = 0; i < 4; ++i) {
      gload_lds16(srcA[i] + koff, An + ldso[i]);
      gload_lds16(srcB[i] + koff, Bn + ldso[i]);
    }
  }
  __builtin_amdgcn_sched_barrier(0);  // pin prefetch issue before compute
  // compute tile t from Ac/Bc (guaranteed resident by t-1's syncthreads)
#pragma unroll
  for (int ks = 0; ks < 2; ++ks) {
    bf16x8 a[8], b[4];
    int kb = ks * 64 + quad * 16;
#pragma unroll
    for (int fr = 0; fr < 8; ++fr) a[fr] = frag_ld(Ac, wm * 128 + fr * 16 + lm, kb);
#pragma unroll
    for (int fc = 0; fc < 4; ++fc) b[fc] = frag_ld(Bc, wn * 64 + fc * 16 + lm, kb);
    __builtin_amdgcn_s_setprio(1);
#pragma unroll
    for (int fr = 0; fr < 8; ++fr)
#pragma unroll
      for (int fc = 0; fc < 4; ++fc)
        acc[fr][fc] = __builtin_amdgcn_mfma_f32_16x16x32_bf16(a[fr], b[fc], acc[fr][fc], 0, 0, 0);
    __builtin_amdgcn_s_setprio(0);
  }
  __syncthreads();  // vmcnt(0): t+1 prefetch landed; barrier: buffers swappable
}

// Requires: M%256==0, N%256==0, K%128==0, grid%8==0.
__global__ __launch_bounds__(512, 2) void gemm256(const short* __restrict__ A,
                                                  const short* __restrict__ B,
                                                  float* __restrict__ C,
                                                  int M, int N, int K) {
  extern __shared__ short lds[];
  short* const A0 = lds;                // 256*64 = 16384 shorts (32 KB) each
  short* const B0 = lds + 16384;
  short* const A1 = lds + 32768;
  short* const B1 = lds + 49152;        // total 65536 shorts = 128 KiB
  int tid = threadIdx.x;
  int wave = tid >> 6, lane = tid & 63;
  int lm = lane & 15, quad = lane >> 4;
  int wm = wave >> 2, wn = wave & 3;    // 2M x 4N wave grid
  // T1 bijective XCD swizzle (grids used are %8==0)
  int nwg = gridDim.x * gridDim.y;
  int wg = blockIdx.y * gridDim.x + blockIdx.x;
  int cpx = nwg >> 3;
  int swz = (wg & 7) * cpx + (wg >> 3);
  int bn = (swz % gridDim.x) * 256;
  int bm = (swz / gridDim.x) * 256;
  int nt = K >> 6;
  // staging: tile = 256 rows x 64 k = 2048 16B-chunks; 4 chunks/thread.
  // chunk c -> row c>>3, k-chunk (c&7)^(row&7) (swizzle involution: LDS dest
  // linear c*16B, global source pre-permuted)
  const short* srcA[4]; const short* srcB[4]; int ldso[4];
#pragma unroll
  for (int i = 0; i < 4; ++i) {
    int c = i * 512 + tid;
    int row = c >> 3, kc = (c & 7) ^ (row & 7);
    srcA[i] = A + (size_t)(bm + row) * K + kc * 8;
    srcB[i] = B + (size_t)(bn + row) * K + kc * 8;
    ldso[i] = c * 8;
  }
  // prologue: stage tile 0 -> buf0
#pragma unroll
  for (int i = 0; i < 4; ++i) {
    gload_lds16(srcA[i], A0 + ldso[i]);
    gload_lds16(srcB[i], B0 + ldso[i]);
  }
  __syncthreads();

  f32x4 acc[8][4] = {};
  for (int t = 0; t < nt; t += 2) {
    tile256(t,     nt, A0, B0, A1, B1, srcA, srcB, ldso, wm, wn, lm, quad, acc);
    tile256(t + 1, nt, A1, B1, A0, B0, srcA, srcB, ldso, wm, wn, lm, quad, acc);
  }
  // C/D layout: col = lane&15, row = quad*4 + reg (m89-verified)
#pragma unroll
  for (int fr = 0; fr < 8; ++fr)
#pragma unroll
    for (int fc = 0; fc < 4; ++fc)
#pragma unroll
      for (int e = 0; e < 4; ++e)
        C[(size_t)(bm + wm * 128 + fr * 16 + quad * 4 + e) * N + (bn + wn * 64 + fc * 16 + lm)] =
            acc[fr][fc][e];
}

// ---------------- RoPE + clamp + split/cast ----------------
// qkv f32 [2048][8192] -> Qb[48][2048][128], Kb[8][2048][128], Vtb[8][128][2048] (bf16)
__global__ void rope_split(const float* __restrict__ qkv, short* __restrict__ Qb,
                           short* __restrict__ Kb, short* __restrict__ Vtb) {
  int idx = blockIdx.x * 256 + threadIdx.x;  // one thread per (t, element-pair)
  int t = idx >> 12;                          // 4096 pairs per row
  int p = idx & 4095;
  int o = p * 2;
  float2 ab = *(const float2*)(qkv + (size_t)t * 8192 + o);
  float a = ab.x, b = ab.y;
  if (o < 7168) {  // q and k get rope; v does not
    int d = o & 127;  // within-head offset (even); pair index i = d/2, exponent 2i/128 = d/128
    float ang = (float)t * exp2f((float)d * (-18.931568569324174f / 128.0f));
    float s, c;
    sincosf(ang, &s, &c);  // accurate range reduction (args up to ~2047 rad)
    float a2 = a * c - b * s;
    float b2 = a * s + b * c;
    a = a2; b = b2;
  }
  a = fminf(8.0f, fmaxf(-8.0f, a));
  b = fminf(8.0f, fmaxf(-8.0f, b));
  short sa = f2bf(a), sb = f2bf(b);
  if (o < 6144) {
    int h = o >> 7, d = o & 127;
    short* q = Qb + (size_t)(h * 2048 + t) * 128 + d;
    q[0] = sa; q[1] = sb;
  } else if (o < 7168) {
    int oo = o - 6144; int h = oo >> 7, d = oo & 127;
    short* k = Kb + (size_t)(h * 2048 + t) * 128 + d;
    k[0] = sa; k[1] = sb;
  } else {
    int oo = o - 7168; int h = oo >> 7, d = oo & 127;
    Vtb[(size_t)(h * 128 + d) * 2048 + t]     = sa;  // transposed store for PV B-frags
    Vtb[(size_t)(h * 128 + d + 1) * 2048 + t] = sb;
  }
}

// ---------------- flash attention (causal, GQA) ----------------
// grid: 1536 1-D blocks, ordered heavy-first (mtile descending) to kill the
// causal-imbalance tail. Wave w owns q rows mtile*64+w*16..+15.
// KV staging is T14 async-split: next tile's global loads issue into registers
// right after the post-stage barrier, so L2/HBM latency hides under the whole
// QK/softmax/PV phase; loop-top ds_writes then hit already-landed registers.
// Out: attn [2048][6144] bf16 row-major (input A of out-projection GEMM).
__global__ __launch_bounds__(256) void flash_attn(const short* __restrict__ Q,
                                                  const short* __restrict__ K,
                                                  const short* __restrict__ Vt,
                                                  short* __restrict__ Ob) {
  __shared__ short Ks[64 * 136];    // K tile [64 kv][128 d], +8 pad (2-way conflicts only)
  __shared__ short Vs[128 * 72];    // V^T tile [128 d][64 kv], +8 pad
  __shared__ short Ps[4][16 * 72];  // per-wave P round-trip (C-layout -> A-layout)
  int bid = blockIdx.x;
  int mtile = 31 - (bid / 48);  // all 48 heads of the heaviest mtile launch first
  int h = bid % 48;
  int hk = h / 6;  // GQA: jnp.repeat -> kv head = h / (48/8)
  int tid = threadIdx.x, wave = tid >> 6, lane = tid & 63;
  int lm = lane & 15, quad = lane >> 4;
  int qrow0 = mtile * 64 + wave * 16;
  // Q fragments (A-layout: m=lane&15, k=quad*8+j), kept in registers across KV loop
  bf16x8 qf[4];
#pragma unroll
  for (int kc = 0; kc < 4; ++kc)
    qf[kc] = *(const bf16x8*)(Q + (size_t)(h * 2048 + qrow0 + lm) * 128 + kc * 32 + quad * 8);
  // per-thread staging addresses (kv0-invariant parts)
  const short* gk[4]; short* lk[4];
  const short* gv[4]; short* lv[4];
#pragma unroll
  for (int i = 0; i < 4; ++i) {
    int c = tid + i * 256;
    int r = c >> 4, ko = (c & 15) * 8;
    gk[i] = K + (size_t)(hk * 2048 + r) * 128 + ko;   // + kv0*128 per tile
    lk[i] = Ks + r * 136 + ko;
    int d = c >> 3, to = (c & 7) * 8;
    gv[i] = Vt + (size_t)(hk * 128 + d) * 2048 + to;  // + kv0 per tile
    lv[i] = Vs + d * 72 + to;
  }
  f32x4 o_acc[8] = {};
  float m_run[4] = {-1e30f, -1e30f, -1e30f, -1e30f};
  float l_run[4] = {0.f, 0.f, 0.f, 0.f};
  const float sc = 0.08838834764831845f;  // 1/sqrt(128)
  int nkv = mtile + 1;                    // causal: kv blocks 0..mtile
  // prologue: issue tile 0's loads
  bf16x8 kst[4], vst[4];
#pragma unroll
  for (int i = 0; i < 4; ++i) {
    kst[i] = *(const bf16x8*)(gk[i]);
    vst[i] = *(const bf16x8*)(gv[i]);
  }
  for (int kb = 0; kb < nkv; ++kb) {
    int kv0 = kb * 64;
    __syncthreads();  // previous iter's LDS reads done before restaging
#pragma unroll
    for (int i = 0; i < 4; ++i) {  // staged regs -> LDS (vmcnt drained by compiler)
      *(bf16x8*)lk[i] = kst[i];
      *(bf16x8*)lv[i] = vst[i];
    }
    __syncthreads();
    if (kb + 1 < nkv) {  // T14: prefetch next tile under this tile's compute
      int kv1 = kv0 + 64;
#pragma unroll
      for (int i = 0; i < 4; ++i) {
        kst[i] = *(const bf16x8*)(gk[i] + (size_t)kv1 * 128);
        vst[i] = *(const bf16x8*)(gv[i] + kv1);
      }
    }
    // S = Q K^T : 4 col-tiles x 4 k-chunks
    f32x4 s[4];
    __builtin_amdgcn_s_setprio(1);
#pragma unroll
    for (int ct = 0; ct < 4; ++ct) {
      f32x4 acc = {};
#pragma unroll
      for (int kc = 0; kc < 4; ++kc) {
        bf16x8 bfr = *(const bf16x8*)(Ks + (ct * 16 + lm) * 136 + kc * 32 + quad * 8);
        acc = __builtin_amdgcn_mfma_f32_16x16x32_bf16(qf[kc], bfr, acc, 0, 0, 0);
      }
      s[ct] = acc;
    }
    __builtin_amdgcn_s_setprio(0);
    // scale; causal mask only needed on the diagonal block (wave-uniform branch)
#pragma unroll
    for (int ct = 0; ct < 4; ++ct)
#pragma unroll
      for (int e = 0; e < 4; ++e) s[ct][e] *= sc;
    if (kb == mtile) {
#pragma unroll
      for (int ct = 0; ct < 4; ++ct) {
        int col = kv0 + ct * 16 + lm;
#pragma unroll
        for (int e = 0; e < 4; ++e) {
          int row = qrow0 + quad * 4 + e;
          if (col > row) s[ct][e] = -1e30f;
        }
      }
    }
    // online softmax: row stats live replicated across the quad's 16 lanes
    float mx[4];
#pragma unroll
    for (int e = 0; e < 4; ++e)
      mx[e] = fmaxf(fmaxf(s[0][e], s[1][e]), fmaxf(s[2][e], s[3][e]));
#pragma unroll
    for (int off = 1; off < 16; off <<= 1)
#pragma unroll
      for (int e = 0; e < 4; ++e) mx[e] = fmaxf(mx[e], __shfl_xor(mx[e], off, 64));
    float alpha[4];
#pragma unroll
    for (int e = 0; e < 4; ++e) {
      float mn = fmaxf(m_run[e], mx[e]);
      alpha[e] = __expf(m_run[e] - mn);
      m_run[e] = mn;
    }
    float rs[4] = {0.f, 0.f, 0.f, 0.f};
#pragma unroll
    for (int ct = 0; ct < 4; ++ct)
#pragma unroll
      for (int e = 0; e < 4; ++e) {
        float pv = __expf(s[ct][e] - m_run[e]);  // masked -> exp(-1e30-m) == 0
        s[ct][e] = pv;
        rs[e] += pv;
      }
#pragma unroll
    for (int off = 1; off < 16; off <<= 1)
#pragma unroll
      for (int e = 0; e < 4; ++e) rs[e] += __shfl_xor(rs[e], off, 64);
#pragma unroll
    for (int e = 0; e < 4; ++e) l_run[e] = l_run[e] * alpha[e] + rs[e];
#pragma unroll
    for (int ot = 0; ot < 8; ++ot)
#pragma unroll
      for (int e = 0; e < 4; ++e) o_acc[ot][e] *= alpha[e];
    // P: C-layout regs -> LDS -> A-layout frags (wave-private buffer, no barrier)
    short* pw = &Ps[wave][0];
#pragma unroll
    for (int ct = 0; ct < 4; ++ct)
#pragma unroll
      for (int e = 0; e < 4; ++e)
        pw[(quad * 4 + e) * 72 + ct * 16 + lm] = f2bf(s[ct][e]);
    __builtin_amdgcn_s_setprio(1);
#pragma unroll
    for (int kc = 0; kc < 2; ++kc) {
      bf16x8 afr = *(const bf16x8*)(pw + lm * 72 + kc * 32 + quad * 8);
#pragma unroll
      for (int ot = 0; ot < 8; ++ot) {
        bf16x8 bfr = *(const bf16x8*)(Vs + (ot * 16 + lm) * 72 + kc * 32 + quad * 8);
        o_acc[ot] = __builtin_amdgcn_mfma_f32_16x16x32_bf16(afr, bfr, o_acc[ot], 0, 0, 0);
      }
    }
    __builtin_amdgcn_s_setprio(0);
  }
  // epilogue: O / l, write [t][h*128+d] bf16
#pragma unroll
  for (int ot = 0; ot < 8; ++ot)
#pragma unroll
    for (int e = 0; e < 4; ++e) {
      float v = o_acc[ot][e] / l_run[e];
      Ob[(size_t)(qrow0 + quad * 4 + e) * 6144 + h * 128 + ot * 16 + lm] = f2bf(v);
    }
}

// ---------------- launch ----------------
extern "C" void kernel_launch(void* const* d_in, const int* in_sizes, int n_in,
                              void* d_out, int out_size, void* d_ws, size_t ws_size,
                              hipStream_t stream) {
  const float* x     = (const float*)d_in[0];
  // d_in[1] = causal_mask: implemented analytically, unused
  const float* w_qkv = (const float*)d_in[2];
  const float* w_out = (const float*)d_in[3];
  float* out = (float*)d_out;

  // workspace layout (bytes):
  short* xb    = (short*)d_ws;                       // 2048*6144 bf16
  short* wqkvb = xb + (size_t)2048 * 6144;           // 8192*6144 bf16
  short* woutb = wqkvb + (size_t)8192 * 6144;        // 6144*6144 bf16
  float* qkvf  = (float*)(woutb + (size_t)6144 * 6144);  // 2048*8192 f32
  short* Qb    = (short*)(qkvf + (size_t)2048 * 8192);   // 48*2048*128
  short* Kb    = Qb + (size_t)48 * 2048 * 128;           // 8*2048*128
  short* Vtb   = Kb + (size_t)8 * 2048 * 128;            // 8*128*2048 (transposed)
  short* attnb = Vtb + (size_t)8 * 128 * 2048;           // 2048*6144

  // 128 KiB dynamic LDS for gemm256 (one-time attribute raise; not a stream op)
  static bool attr_done = false;
  if (!attr_done) {
    (void)hipFuncSetAttribute((const void*)gemm256,
                              hipFuncAttributeMaxDynamicSharedMemorySize, 131072);
    attr_done = true;
  }

  cvt_bf16<<<(2048 * 6144 / 8) / 256, 256, 0, stream>>>(x, xb, 2048 * 6144 / 8);
  cvt_bf16<<<(8192 * 6144 / 8) / 256, 256, 0, stream>>>(w_qkv, wqkvb, 8192 * 6144 / 8);
  cvt_bf16<<<(6144 * 6144 / 8) / 256, 256, 0, stream>>>(w_out, woutb, 6144 * 6144 / 8);

  gemm256<<<dim3(8192 / 256, 2048 / 256), 512, 131072, stream>>>(xb, wqkvb, qkvf, 2048, 8192, 6144);

  rope_split<<<(2048 * 4096) / 256, 256, 0, stream>>>(qkvf, Qb, Kb, Vtb);

  flash_attn<<<dim3(1536), 256, 0, stream>>>(Qb, Kb, Vtb, attnb);

  gemm256<<<dim3(6144 / 256, 2048 / 256), 512, 131072, stream>>>(attnb, woutb, out, 2048, 6144, 6144);
}

// Round 4
// 996.932 us; speedup vs baseline: 1.5712x; 1.5712x over previous
//
#include <hip/hip_runtime.h>

// DBRX attention layer: B=1, T=2048, D_MODEL=6144, NH=48, NKV=8, HD=128,
// rope_base=5e5 full-dim, clamp +-8, causal, f32 in/out, bf16 MFMA compute.

typedef __attribute__((ext_vector_type(8))) short bf16x8;
typedef __attribute__((ext_vector_type(4))) float f32x4;

__device__ inline short f2bf(float f) {
  union { float f; unsigned u; } v; v.f = f;
  unsigned r = v.u + 0x7fffu + ((v.u >> 16) & 1u);  // round-to-nearest-even
  return (short)(r >> 16);
}

// ---------------- f32 -> bf16 convert (8 elems/thread) ----------------
__global__ void cvt_bf16(const float* __restrict__ in, short* __restrict__ out, int n8) {
  int i = blockIdx.x * 256 + threadIdx.x;
  if (i >= n8) return;
  const float4* p = (const float4*)in;
  float4 a = p[2 * i], b = p[2 * i + 1];
  bf16x8 r;
  r[0] = f2bf(a.x); r[1] = f2bf(a.y); r[2] = f2bf(a.z); r[3] = f2bf(a.w);
  r[4] = f2bf(b.x); r[5] = f2bf(b.y); r[6] = f2bf(b.z); r[7] = f2bf(b.w);
  *((bf16x8*)out + i) = r;
}

// ============ bf16 GEMM, B^T input — 3-buffer counted-vmcnt pipeline ==========
// (round-2 verified structure: 220 us, MfmaUtil 41%, bank-conflicts 0)
// A: MxK row-major bf16, B: NxK row-major bf16 (B^T), C: MxN f32.
// BM=256, BN=128, BK=64. 512 thr = 8 waves (4M x 2N), per-wave 64x64 out
// (4x4 frags of 16x16x32). LDS: 3 buffers x (A 32KB + B 16KB) = 144 KiB dynamic.
// Pipeline: while computing tile t (buf t%3), stage tile t+2 (buf (t+2)%3,
// last read at t-1, barrier-separated -> race-free). In-loop wait vmcnt(6)
// keeps tile t+2's 6 loads/thread in flight (T4: never drain). T2: XOR-swizzle
// byte^=(row&7)<<4, linear LDS dest + inverse-swizzled global source (rule 21).
// Round-4 tweak: ALL A-frags (a[4]) are ds_read in phase 1 (they read the
// current tile's buffer, which nothing writes this tile -> safe across the
// barrier); phase 2 enters its MFMA cluster immediately after the barrier.
__device__ __forceinline__ void gload_lds16(const short* g, short* l) {
  __builtin_amdgcn_global_load_lds(
      (const __attribute__((address_space(1))) void*)g,
      (__attribute__((address_space(3))) void*)l, 16, 0, 0);
}

__device__ __forceinline__ bf16x8 frag_ld(const short* buf, int row, int kb) {
  // row in tile rows (128B rows), kb = ks*64 + quad*16 byte offset in K
  int off = row * 128 + (kb ^ ((row & 7) << 4));
  return *(const bf16x8*)((const char*)buf + off);
}

__device__ __forceinline__ void pin_barrier() {
  asm volatile("" ::: "memory");
  __builtin_amdgcn_sched_barrier(0);
  __builtin_amdgcn_s_barrier();
  __builtin_amdgcn_sched_barrier(0);
}

__device__ __forceinline__ void gemm_tile(
    int t, int nt, const short* Ac, const short* Bc, short* Asg, short* Bsg,
    const short* const srcA[4], const int ldsoA[4],
    const short* const srcB[2], const int ldsoB[2],
    int wm, int wn, int lm, int quad, f32x4 acc[4][4]) {
  const bool stage = (t + 2 < nt);
  const int koff = (t + 2) << 6;  // element k-offset of staged tile
  // ---- phase 1: ds-read ALL A frags + all B; stage A of t+2; 16 MFMA ----
  bf16x8 a[4][2], b[4][2];
#pragma unroll
  for (int fr = 0; fr < 4; ++fr)
#pragma unroll
    for (int ks = 0; ks < 2; ++ks)
      a[fr][ks] = frag_ld(Ac, wm * 64 + fr * 16 + lm, ks * 64 + quad * 16);
#pragma unroll
  for (int fc = 0; fc < 4; ++fc)
#pragma unroll
    for (int ks = 0; ks < 2; ++ks)
      b[fc][ks] = frag_ld(Bc, wn * 64 + fc * 16 + lm, ks * 64 + quad * 16);
  if (stage) {
#pragma unroll
    for (int i = 0; i < 4; ++i) gload_lds16(srcA[i] + koff, Asg + ldsoA[i]);
  }
  pin_barrier();
  __builtin_amdgcn_s_setprio(1);
#pragma unroll
  for (int fr = 0; fr < 2; ++fr)
#pragma unroll
    for (int fc = 0; fc < 4; ++fc) {
      acc[fr][fc] = __builtin_amdgcn_mfma_f32_16x16x32_bf16(a[fr][0], b[fc][0], acc[fr][fc], 0, 0, 0);
      acc[fr][fc] = __builtin_amdgcn_mfma_f32_16x16x32_bf16(a[fr][1], b[fc][1], acc[fr][fc], 0, 0, 0);
    }
  __builtin_amdgcn_s_setprio(0);
  pin_barrier();
  // ---- phase 2: stage B of t+2; vmcnt; 16 MFMA (frags already in regs) ----
  if (stage) {
#pragma unroll
    for (int i = 0; i < 2; ++i) gload_lds16(srcB[i] + koff, Bsg + ldsoB[i]);
    // outstanding/thread: t+1's 6 (oldest) + t+2's 6 -> wait leaves t+2 in flight
    asm volatile("s_waitcnt vmcnt(6)" ::: "memory");
  } else {
    asm volatile("s_waitcnt vmcnt(0)" ::: "memory");  // epilogue drain (last 2 tiles)
  }
  pin_barrier();  // after this barrier, ALL waves' tile-(t+1) chunks are in LDS
  __builtin_amdgcn_s_setprio(1);
#pragma unroll
  for (int fr = 0; fr < 2; ++fr)
#pragma unroll
    for (int fc = 0; fc < 4; ++fc) {
      acc[fr + 2][fc] = __builtin_amdgcn_mfma_f32_16x16x32_bf16(a[fr + 2][0], b[fc][0], acc[fr + 2][fc], 0, 0, 0);
      acc[fr + 2][fc] = __builtin_amdgcn_mfma_f32_16x16x32_bf16(a[fr + 2][1], b[fc][1], acc[fr + 2][fc], 0, 0, 0);
    }
  __builtin_amdgcn_s_setprio(0);
  pin_barrier();
}

// Requires: M%256==0, N%128==0, K%192==0 (K/64 divisible by 3), grid%8==0.
__global__ __launch_bounds__(512, 2) void gemm256(const short* __restrict__ A,
                                                  const short* __restrict__ B,
                                                  float* __restrict__ C,
                                                  int M, int N, int K) {
  extern __shared__ short lds[];
  short* const A0 = lds;                // 256*64 = 16384 shorts each
  short* const A1 = lds + 16384;
  short* const A2 = lds + 32768;
  short* const B0 = lds + 49152;        // 128*64 = 8192 shorts each
  short* const B1 = lds + 57344;
  short* const B2 = lds + 65536;        // total 73728 shorts = 144 KiB
  int tid = threadIdx.x;
  int wave = tid >> 6, lane = tid & 63;
  int lm = lane & 15, quad = lane >> 4;
  int wm = wave >> 1, wn = wave & 1;
  // T1 bijective XCD swizzle (grid sizes used are %8==0)
  int nwg = gridDim.x * gridDim.y;
  int wg = blockIdx.y * gridDim.x + blockIdx.x;
  int cpx = nwg >> 3;
  int swz = (wg & 7) * cpx + (wg >> 3);
  int bn = (swz % gridDim.x) * 128;
  int bm = (swz / gridDim.x) * 256;
  int nt = K >> 6;
  // staging descriptors: chunk c -> row c>>3, k-chunk (c&7)^(row&7) (swizzle
  // involution: LDS dest stays linear c*16B, source pre-permuted)
  const short* srcA[4]; int ldsoA[4];
#pragma unroll
  for (int i = 0; i < 4; ++i) {
    int c = i * 512 + tid;
    int row = c >> 3, kc = (c & 7) ^ (row & 7);
    srcA[i] = A + (size_t)(bm + row) * K + kc * 8;
    ldsoA[i] = c * 8;
  }
  const short* srcB[2]; int ldsoB[2];
#pragma unroll
  for (int i = 0; i < 2; ++i) {
    int c = i * 512 + tid;
    int row = c >> 3, kc = (c & 7) ^ (row & 7);
    srcB[i] = B + (size_t)(bn + row) * K + kc * 8;
    ldsoB[i] = c * 8;
  }
  // prologue: stage tile0 -> buf0, tile1 -> buf1; wait own tile0 loads; barrier
#pragma unroll
  for (int i = 0; i < 4; ++i) gload_lds16(srcA[i], A0 + ldsoA[i]);
#pragma unroll
  for (int i = 0; i < 2; ++i) gload_lds16(srcB[i], B0 + ldsoB[i]);
#pragma unroll
  for (int i = 0; i < 4; ++i) gload_lds16(srcA[i] + 64, A1 + ldsoA[i]);
#pragma unroll
  for (int i = 0; i < 2; ++i) gload_lds16(srcB[i] + 64, B1 + ldsoB[i]);
  asm volatile("s_waitcnt vmcnt(6)" ::: "memory");
  __builtin_amdgcn_s_barrier();
  __builtin_amdgcn_sched_barrier(0);

  f32x4 acc[4][4] = {};
  for (int t = 0; t < nt; t += 3) {
    gemm_tile(t,     nt, A0, B0, A2, B2, srcA, ldsoA, srcB, ldsoB, wm, wn, lm, quad, acc);
    gemm_tile(t + 1, nt, A1, B1, A0, B0, srcA, ldsoA, srcB, ldsoB, wm, wn, lm, quad, acc);
    gemm_tile(t + 2, nt, A2, B2, A1, B1, srcA, ldsoA, srcB, ldsoB, wm, wn, lm, quad, acc);
  }
  // C/D layout: col = lane&15, row = quad*4 + reg (m89-verified)
#pragma unroll
  for (int fr = 0; fr < 4; ++fr)
#pragma unroll
    for (int fc = 0; fc < 4; ++fc)
#pragma unroll
      for (int e = 0; e < 4; ++e)
        C[(size_t)(bm + wm * 64 + fr * 16 + quad * 4 + e) * N + (bn + wn * 64 + fc * 16 + lm)] =
            acc[fr][fc][e];
}

// ---------------- RoPE + clamp + split/cast ----------------
// qkv f32 [2048][8192] -> Qb[48][2048][128], Kb[8][2048][128], Vtb[8][128][2048] (bf16)
__global__ void rope_split(const float* __restrict__ qkv, short* __restrict__ Qb,
                           short* __restrict__ Kb, short* __restrict__ Vtb) {
  int idx = blockIdx.x * 256 + threadIdx.x;  // one thread per (t, element-pair)
  int t = idx >> 12;                          // 4096 pairs per row
  int p = idx & 4095;
  int o = p * 2;
  float2 ab = *(const float2*)(qkv + (size_t)t * 8192 + o);
  float a = ab.x, b = ab.y;
  if (o < 7168) {  // q and k get rope; v does not
    int d = o & 127;  // within-head offset (even); pair index i = d/2, exponent 2i/128 = d/128
    float ang = (float)t * exp2f((float)d * (-18.931568569324174f / 128.0f));
    float s, c;
    sincosf(ang, &s, &c);  // accurate range reduction (args up to ~2047 rad)
    float a2 = a * c - b * s;
    float b2 = a * s + b * c;
    a = a2; b = b2;
  }
  a = fminf(8.0f, fmaxf(-8.0f, a));
  b = fminf(8.0f, fmaxf(-8.0f, b));
  short sa = f2bf(a), sb = f2bf(b);
  if (o < 6144) {
    int h = o >> 7, d = o & 127;
    short* q = Qb + (size_t)(h * 2048 + t) * 128 + d;
    q[0] = sa; q[1] = sb;
  } else if (o < 7168) {
    int oo = o - 6144; int h = oo >> 7, d = oo & 127;
    short* k = Kb + (size_t)(h * 2048 + t) * 128 + d;
    k[0] = sa; k[1] = sb;
  } else {
    int oo = o - 7168; int h = oo >> 7, d = oo & 127;
    Vtb[(size_t)(h * 128 + d) * 2048 + t]     = sa;  // transposed store for PV B-frags
    Vtb[(size_t)(h * 128 + d + 1) * 2048 + t] = sb;
  }
}

// ---------------- flash attention (causal, GQA) ----------------
// grid: 1536 1-D blocks, ordered heavy-first (mtile descending) to kill the
// causal-imbalance tail. Wave w owns q rows mtile*64+w*16..+15.
// KV staging is T14 async-split: next tile's global loads issue into registers
// right after the post-stage barrier, so L2/HBM latency hides under the whole
// QK/softmax/PV phase; loop-top ds_writes then hit already-landed registers.
// Out: attn [2048][6144] bf16 row-major (input A of out-projection GEMM).
__global__ __launch_bounds__(256) void flash_attn(const short* __restrict__ Q,
                                                  const short* __restrict__ K,
                                                  const short* __restrict__ Vt,
                                                  short* __restrict__ Ob) {
  __shared__ short Ks[64 * 136];    // K tile [64 kv][128 d], +8 pad (2-way conflicts only)
  __shared__ short Vs[128 * 72];    // V^T tile [128 d][64 kv], +8 pad
  __shared__ short Ps[4][16 * 72];  // per-wave P round-trip (C-layout -> A-layout)
  int bid = blockIdx.x;
  int mtile = 31 - (bid / 48);  // all 48 heads of the heaviest mtile launch first
  int h = bid % 48;
  int hk = h / 6;  // GQA: jnp.repeat -> kv head = h / (48/8)
  int tid = threadIdx.x, wave = tid >> 6, lane = tid & 63;
  int lm = lane & 15, quad = lane >> 4;
  int qrow0 = mtile * 64 + wave * 16;
  // Q fragments (A-layout: m=lane&15, k=quad*8+j), kept in registers across KV loop
  bf16x8 qf[4];
#pragma unroll
  for (int kc = 0; kc < 4; ++kc)
    qf[kc] = *(const bf16x8*)(Q + (size_t)(h * 2048 + qrow0 + lm) * 128 + kc * 32 + quad * 8);
  // per-thread staging addresses (kv0-invariant parts)
  const short* gk[4]; short* lk[4];
  const short* gv[4]; short* lv[4];
#pragma unroll
  for (int i = 0; i < 4; ++i) {
    int c = tid + i * 256;
    int r = c >> 4, ko = (c & 15) * 8;
    gk[i] = K + (size_t)(hk * 2048 + r) * 128 + ko;   // + kv0*128 per tile
    lk[i] = Ks + r * 136 + ko;
    int d = c >> 3, to = (c & 7) * 8;
    gv[i] = Vt + (size_t)(hk * 128 + d) * 2048 + to;  // + kv0 per tile
    lv[i] = Vs + d * 72 + to;
  }
  f32x4 o_acc[8] = {};
  float m_run[4] = {-1e30f, -1e30f, -1e30f, -1e30f};
  float l_run[4] = {0.f, 0.f, 0.f, 0.f};
  const float sc = 0.08838834764831845f;  // 1/sqrt(128)
  int nkv = mtile + 1;                    // causal: kv blocks 0..mtile
  // prologue: issue tile 0's loads
  bf16x8 kst[4], vst[4];
#pragma unroll
  for (int i = 0; i < 4; ++i) {
    kst[i] = *(const bf16x8*)(gk[i]);
    vst[i] = *(const bf16x8*)(gv[i]);
  }
  for (int kb = 0; kb < nkv; ++kb) {
    int kv0 = kb * 64;
    __syncthreads();  // previous iter's LDS reads done before restaging
#pragma unroll
    for (int i = 0; i < 4; ++i) {  // staged regs -> LDS (vmcnt drained by compiler)
      *(bf16x8*)lk[i] = kst[i];
      *(bf16x8*)lv[i] = vst[i];
    }
    __syncthreads();
    if (kb + 1 < nkv) {  // T14: prefetch next tile under this tile's compute
      int kv1 = kv0 + 64;
#pragma unroll
      for (int i = 0; i < 4; ++i) {
        kst[i] = *(const bf16x8*)(gk[i] + (size_t)kv1 * 128);
        vst[i] = *(const bf16x8*)(gv[i] + kv1);
      }
    }
    // S = Q K^T : 4 col-tiles x 4 k-chunks
    f32x4 s[4];
    __builtin_amdgcn_s_setprio(1);
#pragma unroll
    for (int ct = 0; ct < 4; ++ct) {
      f32x4 acc = {};
#pragma unroll
      for (int kc = 0; kc < 4; ++kc) {
        bf16x8 bfr = *(const bf16x8*)(Ks + (ct * 16 + lm) * 136 + kc * 32 + quad * 8);
        acc = __builtin_amdgcn_mfma_f32_16x16x32_bf16(qf[kc], bfr, acc, 0, 0, 0);
      }
      s[ct] = acc;
    }
    __builtin_amdgcn_s_setprio(0);
    // scale; causal mask only needed on the diagonal block (wave-uniform branch)
#pragma unroll
    for (int ct = 0; ct < 4; ++ct)
#pragma unroll
      for (int e = 0; e < 4; ++e) s[ct][e] *= sc;
    if (kb == mtile) {
#pragma unroll
      for (int ct = 0; ct < 4; ++ct) {
        int col = kv0 + ct * 16 + lm;
#pragma unroll
        for (int e = 0; e < 4; ++e) {
          int row = qrow0 + quad * 4 + e;
          if (col > row) s[ct][e] = -1e30f;
        }
      }
    }
    // online softmax: row stats live replicated across the quad's 16 lanes
    float mx[4];
#pragma unroll
    for (int e = 0; e < 4; ++e)
      mx[e] = fmaxf(fmaxf(s[0][e], s[1][e]), fmaxf(s[2][e], s[3][e]));
#pragma unroll
    for (int off = 1; off < 16; off <<= 1)
#pragma unroll
      for (int e = 0; e < 4; ++e) mx[e] = fmaxf(mx[e], __shfl_xor(mx[e], off, 64));
    float alpha[4];
#pragma unroll
    for (int e = 0; e < 4; ++e) {
      float mn = fmaxf(m_run[e], mx[e]);
      alpha[e] = __expf(m_run[e] - mn);
      m_run[e] = mn;
    }
    float rs[4] = {0.f, 0.f, 0.f, 0.f};
#pragma unroll
    for (int ct = 0; ct < 4; ++ct)
#pragma unroll
      for (int e = 0; e < 4; ++e) {
        float pv = __expf(s[ct][e] - m_run[e]);  // masked -> exp(-1e30-m) == 0
        s[ct][e] = pv;
        rs[e] += pv;
      }
#pragma unroll
    for (int off = 1; off < 16; off <<= 1)
#pragma unroll
      for (int e = 0; e < 4; ++e) rs[e] += __shfl_xor(rs[e], off, 64);
#pragma unroll
    for (int e = 0; e < 4; ++e) l_run[e] = l_run[e] * alpha[e] + rs[e];
#pragma unroll
    for (int ot = 0; ot < 8; ++ot)
#pragma unroll
      for (int e = 0; e < 4; ++e) o_acc[ot][e] *= alpha[e];
    // P: C-layout regs -> LDS -> A-layout frags (wave-private buffer, no barrier)
    short* pw = &Ps[wave][0];
#pragma unroll
    for (int ct = 0; ct < 4; ++ct)
#pragma unroll
      for (int e = 0; e < 4; ++e)
        pw[(quad * 4 + e) * 72 + ct * 16 + lm] = f2bf(s[ct][e]);
    __builtin_amdgcn_s_setprio(1);
#pragma unroll
    for (int kc = 0; kc < 2; ++kc) {
      bf16x8 afr = *(const bf16x8*)(pw + lm * 72 + kc * 32 + quad * 8);
#pragma unroll
      for (int ot = 0; ot < 8; ++ot) {
        bf16x8 bfr = *(const bf16x8*)(Vs + (ot * 16 + lm) * 72 + kc * 32 + quad * 8);
        o_acc[ot] = __builtin_amdgcn_mfma_f32_16x16x32_bf16(afr, bfr, o_acc[ot], 0, 0, 0);
      }
    }
    __builtin_amdgcn_s_setprio(0);
  }
  // epilogue: O / l, write [t][h*128+d] bf16
#pragma unroll
  for (int ot = 0; ot < 8; ++ot)
#pragma unroll
    for (int e = 0; e < 4; ++e) {
      float v = o_acc[ot][e] / l_run[e];
      Ob[(size_t)(qrow0 + quad * 4 + e) * 6144 + h * 128 + ot * 16 + lm] = f2bf(v);
    }
}

// ---------------- launch ----------------
extern "C" void kernel_launch(void* const* d_in, const int* in_sizes, int n_in,
                              void* d_out, int out_size, void* d_ws, size_t ws_size,
                              hipStream_t stream) {
  const float* x     = (const float*)d_in[0];
  // d_in[1] = causal_mask: implemented analytically, unused
  const float* w_qkv = (const float*)d_in[2];
  const float* w_out = (const float*)d_in[3];
  float* out = (float*)d_out;

  // workspace layout (bytes):
  short* xb    = (short*)d_ws;                       // 2048*6144 bf16
  short* wqkvb = xb + (size_t)2048 * 6144;           // 8192*6144 bf16
  short* woutb = wqkvb + (size_t)8192 * 6144;        // 6144*6144 bf16
  float* qkvf  = (float*)(woutb + (size_t)6144 * 6144);  // 2048*8192 f32
  short* Qb    = (short*)(qkvf + (size_t)2048 * 8192);   // 48*2048*128
  short* Kb    = Qb + (size_t)48 * 2048 * 128;           // 8*2048*128
  short* Vtb   = Kb + (size_t)8 * 2048 * 128;            // 8*128*2048 (transposed)
  short* attnb = Vtb + (size_t)8 * 128 * 2048;           // 2048*6144

  // 144 KiB dynamic LDS for gemm256 (one-time attribute raise; not a stream op)
  static bool attr_done = false;
  if (!attr_done) {
    (void)hipFuncSetAttribute((const void*)gemm256,
                              hipFuncAttributeMaxDynamicSharedMemorySize, 147456);
    attr_done = true;
  }

  cvt_bf16<<<(2048 * 6144 / 8) / 256, 256, 0, stream>>>(x, xb, 2048 * 6144 / 8);
  cvt_bf16<<<(8192 * 6144 / 8) / 256, 256, 0, stream>>>(w_qkv, wqkvb, 8192 * 6144 / 8);
  cvt_bf16<<<(6144 * 6144 / 8) / 256, 256, 0, stream>>>(w_out, woutb, 6144 * 6144 / 8);

  gemm256<<<dim3(8192 / 128, 2048 / 256), 512, 147456, stream>>>(xb, wqkvb, qkvf, 2048, 8192, 6144);

  rope_split<<<(2048 * 4096) / 256, 256, 0, stream>>>(qkvf, Qb, Kb, Vtb);

  flash_attn<<<dim3(1536), 256, 0, stream>>>(Qb, Kb, Vtb, attnb);

  gemm256<<<dim3(6144 / 128, 2048 / 256), 512, 147456, stream>>>(attnb, woutb, out, 2048, 6144, 6144);
}